// Round 1
// baseline (531.599 us; speedup 1.0000x reference)
//
#include <hip/hip_runtime.h>
#include <hip/hip_bf16.h>

// Bilinear resample with zero-padding OOB semantics (tf resampler behavior).
// imgs: (B,H,W,1) f32, dvfs: (B,H,W,2) f32 (ch0 = x offset, ch1 = y offset)
// out:  (B,H,W,1) f32
// B=32, H=W=1024 for this problem instance.

#define H_DIM 1024
#define W_DIM 1024

__device__ __forceinline__ float gather_zp(const float* __restrict__ img,
                                           int yy, int xx) {
    bool valid = (xx >= 0) & (xx < W_DIM) & (yy >= 0) & (yy < H_DIM);
    int xc = min(max(xx, 0), W_DIM - 1);
    int yc = min(max(yy, 0), H_DIM - 1);
    float v = img[yc * W_DIM + xc];
    return valid ? v : 0.0f;
}

__global__ __launch_bounds__(256) void bilerp_kernel(
        const float* __restrict__ imgs,
        const float* __restrict__ dvfs,
        float* __restrict__ out,
        long long total_pixels) {
    long long tid = (long long)blockIdx.x * blockDim.x + threadIdx.x;
    long long base = tid * 4;  // first of 4 consecutive pixels (same row: W%4==0)
    if (base >= total_pixels) return;

    const int hw = H_DIM * W_DIM;
    int b   = (int)(base / hw);
    int rem = (int)(base % hw);
    int y   = rem / W_DIM;
    int x   = rem % W_DIM;

    const float* __restrict__ img = imgs + (long long)b * hw;

    // 8 dvfs floats for the 4 pixels: two coalesced float4 loads
    const float4* dvf4 = (const float4*)(dvfs + base * 2);
    float4 d0 = dvf4[0];   // (dx0,dy0,dx1,dy1)
    float4 d1 = dvf4[1];   // (dx2,dy2,dx3,dy3)
    float dx[4] = {d0.x, d0.z, d1.x, d1.z};
    float dy[4] = {d0.y, d0.w, d1.y, d1.w};

    float4 res;
    float* rp = &res.x;
    #pragma unroll
    for (int i = 0; i < 4; ++i) {
        float fx = (float)(x + i) + dx[i];
        float fy = (float)y       + dy[i];
        float x0f = floorf(fx);
        float y0f = floorf(fy);
        float wx = fx - x0f;
        float wy = fy - y0f;
        int x0 = (int)x0f;
        int y0 = (int)y0f;
        int x1 = x0 + 1;
        int y1 = y0 + 1;

        float v00 = gather_zp(img, y0, x0);
        float v01 = gather_zp(img, y0, x1);
        float v10 = gather_zp(img, y1, x0);
        float v11 = gather_zp(img, y1, x1);

        rp[i] = v00 * (1.0f - wx) * (1.0f - wy)
              + v01 * wx          * (1.0f - wy)
              + v10 * (1.0f - wx) * wy
              + v11 * wx          * wy;
    }

    *(float4*)(out + base) = res;
}

extern "C" void kernel_launch(void* const* d_in, const int* in_sizes, int n_in,
                              void* d_out, int out_size, void* d_ws, size_t ws_size,
                              hipStream_t stream) {
    const float* imgs = (const float*)d_in[0];
    const float* dvfs = (const float*)d_in[1];
    float* out = (float*)d_out;

    long long total_pixels = (long long)out_size;  // B*H*W*1
    long long n_threads = (total_pixels + 3) / 4;
    int block = 256;
    long long grid = (n_threads + block - 1) / block;

    bilerp_kernel<<<(dim3)(unsigned)grid, block, 0, stream>>>(imgs, dvfs, out, total_pixels);
}